// Round 20
// baseline (59.553 us; speedup 1.0000x reference)
//
#include <hip/hip_runtime.h>

#define NB   8192
#define NA   32
#define DIN  8
#define HID  64
#define DOUT 8

#define LOG2E 1.44269504088896340736f

typedef float     v4f __attribute__((ext_vector_type(4)));
typedef __fp16    v2fp __attribute__((ext_vector_type(2)));
typedef _Float16  v2h __attribute__((ext_vector_type(2)));
typedef _Float16  v4h __attribute__((ext_vector_type(4)));
typedef _Float16  v8h __attribute__((ext_vector_type(8)));

__device__ __forceinline__ float silu_f(float x) {
    return __fdividef(x, 1.0f + __expf(-x));
}

__device__ __forceinline__ v2h pkrtz(float a, float b) {
    v2fp r = __builtin_amdgcn_cvt_pkrtz(a, b);
    return __builtin_bit_cast(v2h, r);
}

__device__ __forceinline__ v4h cvt4(v4f a) {
    v2h lo = pkrtz(a[0], a[1]);
    v2h hi = pkrtz(a[2], a[3]);
    return __builtin_shufflevector(lo, hi, 0, 1, 2, 3);
}

__device__ __forceinline__ v8h cvt8(v4f a, v4f b) {
    v4h x = cvt4(a);
    v4h y = cvt4(b);
    return __builtin_shufflevector(x, y, 0, 1, 2, 3, 4, 5, 6, 7);
}

__device__ __forceinline__ v4h silu_cvt4(v4f a) {
    v4f s;
    s[0] = silu_f(a[0]); s[1] = silu_f(a[1]);
    s[2] = silu_f(a[2]); s[3] = silu_f(a[3]);
    return cvt4(s);
}

// silu then scale (for Q: scale = log2e so S' = S*log2e and softmax uses exp2)
__device__ __forceinline__ v4h silu_scale_cvt4(v4f a, float sc) {
    v4f s;
    s[0] = silu_f(a[0]) * sc; s[1] = silu_f(a[1]) * sc;
    s[2] = silu_f(a[2]) * sc; s[3] = silu_f(a[3]) * sc;
    return cvt4(s);
}

__device__ __forceinline__ v8h cat(v4h a, v4h b) {
    return __builtin_shufflevector(a, b, 0, 1, 2, 3, 4, 5, 6, 7);
}

// Known-good reductions (r16). permlane*_swap BANNED (r15/r17 NaN).
__device__ __forceinline__ float redmax64(float x) {
    x = fmaxf(x, __shfl_xor(x, 16, 64));
    return fmaxf(x, __shfl_xor(x, 32, 64));
}
__device__ __forceinline__ float redsum64(float x) {
    x += __shfl_xor(x, 16, 64);
    return x + __shfl_xor(x, 32, 64);
}

// 3-ary max groupings -> clang fuses fmaxf(fmaxf(a,b),c) to v_max3_f32
__device__ __forceinline__ float max3f(float a, float b, float c) {
    return fmaxf(fmaxf(a, b), c);
}

#define MFMA16(A, B, C) __builtin_amdgcn_mfma_f32_16x16x16f16((A), (B), (C), 0, 0, 0)
#define MFMA32(A, B, C) __builtin_amdgcn_mfma_f32_16x16x32_f16((A), (B), (C), 0, 0, 0)

// ONE item per wave, tail-only liveness (r19 base). This round: exp2-form
// softmax (Q pre-scaled by log2e -> exp2 without range-reduction mul) and
// v_max3-shaped max tree. Pure VALU op-count cut; softmax math identical.
__global__ __launch_bounds__(256, 4) void attn_mfma_kernel(
    const float* __restrict__ x,      // (NB, NA, DIN)
    const float* __restrict__ lap,    // (NB, NA)
    const float* __restrict__ W_in,   // (HID, DIN)
    const float* __restrict__ b_in,   // (HID)
    const float* __restrict__ Aq,     // (HID, HID)
    const float* __restrict__ Ak,     // (HID, HID)
    const float* __restrict__ Av,     // (HID, HID)
    const float* __restrict__ W_out,  // (DOUT, HID)
    const float* __restrict__ b_out,  // (DOUT)
    float* __restrict__ out)          // (NB, DOUT)
{
    // Paired frag-ordered f16 weights: [mat][it*2+c][lane][8]   (24 KB)
    __shared__ _Float16 wlds[3][8][64][8];

    const int t  = threadIdx.x;
    const int l  = t & 63;
    const int w  = t >> 6;          // 0..3
    const int lm = l & 15;
    const int lg = l >> 4;

    // ---- stage Aq/Ak/Av into LDS as paired f16 frags (2 fids per wave) ----
    {
        const float* mats[3] = {Aq, Ak, Av};
        #pragma unroll
        for (int m = 0; m < 3; ++m)
            #pragma unroll
            for (int f = 0; f < 2; ++f) {
                const int fid = w * 2 + f;          // it = w, c = f
                const float* base = mats[m] + (lm + 16 * w) * 64 + 32 * f + 4 * lg;
                *(v8h*)&wlds[m][fid][l][0] =
                    cvt8(*(const v4f*)base, *(const v4f*)(base + 16));
            }
    }

    // ---- h-stage register frags only (tail values loaded later) ----
    v4h zh = {};
    v4f zf = {};
    v4h winf[4];
    #pragma unroll
    for (int jt = 0; jt < 4; ++jt) {
        v4h wf = zh;
        if (lg < 2)       wf = cvt4(*(const v4f*)(W_in + (lm + 16 * jt) * 8 + 4 * lg));
        else if (lg == 2) wf[0] = (_Float16)b_in[lm + 16 * jt];
        winf[jt] = wf;
    }
    v4h onef = zh;
    if (lg == 2) onef[0] = (_Float16)1.0f;   // the k=8 "bias column" of x

    __syncthreads();   // the only block barrier

    const int b = blockIdx.x * 4 + w;   // one item per wave, 2048*4 == NB

    float lap_n[2];                      // lap by lane n=lm+16nt (h stage)
    lap_n[0] = lap[b * 32 + lm];
    lap_n[1] = lap[b * 32 + 16 + lm];

    // xf[nt]: B-frag x^T[k=d][n=lm+16nt]; k=8 slot = 1.0 (bias column)
    v4h xf[2];
    #pragma unroll
    for (int nt = 0; nt < 2; ++nt)
        xf[nt] = (lg < 2) ? cvt4(*(const v4f*)(x + b * 256 + (lm + 16 * nt) * 8 + 4 * lg))
                          : onef;

    // ---- h^T: C[jt][nt] reg r = h[n=lm+16nt][j=4lg+r+16jt] ----
    v8h hf8[2][2];
    #pragma unroll
    for (int nt = 0; nt < 2; ++nt)
        #pragma unroll
        for (int c = 0; c < 2; ++c) {
            v4f h0 = MFMA16(winf[2 * c],     xf[nt], zf);
            v4f h1 = MFMA16(winf[2 * c + 1], xf[nt], zf);
            v4f s0, s1;
            #pragma unroll
            for (int r = 0; r < 4; ++r) {
                s0[r] = silu_f(h0[r]) * lap_n[nt];
                s1[r] = silu_f(h1[r]) * lap_n[nt];
            }
            hf8[nt][c] = cat(cvt4(s0), cvt4(s1));
        }

    // ---- QT[n][i] = silu(h @ Aq^T) * log2e  (K=32; scale folds into silu) ----
    v8h qf8[4];
    {
        v4f acc[2][4] = {};
        #pragma unroll
        for (int it = 0; it < 4; ++it)
            #pragma unroll
            for (int c = 0; c < 2; ++c) {
                v8h bw = *(v8h*)&wlds[0][it * 2 + c][l][0];
                #pragma unroll
                for (int nt = 0; nt < 2; ++nt)
                    acc[nt][it] = MFMA32(hf8[nt][c], bw, acc[nt][it]);
            }
        #pragma unroll
        for (int it = 0; it < 4; ++it)
            qf8[it] = cat(silu_scale_cvt4(acc[0][it], LOG2E),
                          silu_scale_cvt4(acc[1][it], LOG2E));
    }
    // ---- KT[n][i] = silu(h @ Ak^T) ----
    v8h kf8[4];
    {
        v4f acc[2][4] = {};
        #pragma unroll
        for (int it = 0; it < 4; ++it)
            #pragma unroll
            for (int c = 0; c < 2; ++c) {
                v8h bw = *(v8h*)&wlds[1][it * 2 + c][l][0];
                #pragma unroll
                for (int nt = 0; nt < 2; ++nt)
                    acc[nt][it] = MFMA32(hf8[nt][c], bw, acc[nt][it]);
            }
        #pragma unroll
        for (int it = 0; it < 4; ++it)
            kf8[it] = cat(silu_cvt4(acc[0][it]), silu_cvt4(acc[1][it]));
    }
    // ---- V[i][n] = silu(Av @ h^T) ----  (h dies here)
    v8h vf8[2][2];
    {
        v4f acc[4][2] = {};
        #pragma unroll
        for (int it = 0; it < 4; ++it)
            #pragma unroll
            for (int c = 0; c < 2; ++c) {
                v8h aw = *(v8h*)&wlds[2][it * 2 + c][l][0];
                #pragma unroll
                for (int nt = 0; nt < 2; ++nt)
                    acc[it][nt] = MFMA32(aw, hf8[nt][c], acc[it][nt]);
            }
        #pragma unroll
        for (int c = 0; c < 2; ++c)
            #pragma unroll
            for (int nt = 0; nt < 2; ++nt)
                vf8[c][nt] = cat(silu_cvt4(acc[2 * c][nt]), silu_cvt4(acc[2 * c + 1][nt]));
    }

    // ---- tail-only loads (liveness starts here) ----
    v4h woutf[4];
    #pragma unroll
    for (int ks = 0; ks < 4; ++ks)
        woutf[ks] = (lm < 8) ? cvt4(*(const v4f*)(W_out + lm * 64 + 16 * ks + 4 * lg)) : zh;
    const float boutf = (lm < 8) ? b_out[lm] : 0.0f;
    v4f lapv[2];
    lapv[0] = *(const v4f*)(lap + b * 32 + 4 * lg);
    lapv[1] = *(const v4f*)(lap + b * 32 + 16 + 4 * lg);

    // ---- streamed tail: per i-tile, S'-col -> exp2-softmax -> PV -> Wout ----
    v4f ya[2] = {};
    #pragma unroll
    for (int it = 0; it < 4; ++it) {
        v4f s[4];   // S' = S * log2e (Q pre-scaled)
        #pragma unroll
        for (int jt = 0; jt < 4; ++jt)
            s[jt] = MFMA32(kf8[jt], qf8[it], zf);

        // max tree in 3-ary groups (v_max3_f32)
        float m0 = max3f(s[0][0], s[0][1], s[0][2]);
        float m1 = max3f(s[0][3], s[1][0], s[1][1]);
        float m2 = max3f(s[1][2], s[1][3], s[2][0]);
        float m3 = max3f(s[2][1], s[2][2], s[2][3]);
        float m4 = max3f(s[3][0], s[3][1], s[3][2]);
        float mx = fmaxf(max3f(m0, m1, m2), max3f(m3, m4, s[3][3]));
        mx = redmax64(mx);

        // e = 2^(s' - mx')  == exp(S - mx): no range-reduction mul needed
        float sum = 0.0f;
        #pragma unroll
        for (int jt = 0; jt < 4; ++jt)
            #pragma unroll
            for (int r = 0; r < 4; ++r) {
                float e = exp2f(s[jt][r] - mx);
                s[jt][r] = e;
                sum += e;
            }
        sum = redsum64(sum);
        const float inv = __fdividef(1.0f, sum);
        v4h pf[4];
        #pragma unroll
        for (int jt = 0; jt < 4; ++jt) pf[jt] = cvt4(s[jt] * inv);

        v4f pv[2] = {};
        #pragma unroll
        for (int c = 0; c < 2; ++c) {
            v8h pf8 = cat(pf[2 * c], pf[2 * c + 1]);
            #pragma unroll
            for (int nt = 0; nt < 2; ++nt)
                pv[nt] = MFMA32(pf8, vf8[c][nt], pv[nt]);
        }
        #pragma unroll
        for (int nt = 0; nt < 2; ++nt)
            ya[nt] = MFMA16(silu_cvt4(pv[nt]), woutf[it], ya[nt]);
    }

    // ---- y = silu(ya + b_out) * lap ; mean over n ----
    float acc = 0.0f;
    #pragma unroll
    for (int nt = 0; nt < 2; ++nt)
        #pragma unroll
        for (int r = 0; r < 4; ++r)
            acc += silu_f(ya[nt][r] + boutf) * lapv[nt][r];
    acc = redsum64(acc);
    if (l < 8) out[b * DOUT + l] = acc * (1.0f / NA);
}

extern "C" void kernel_launch(void* const* d_in, const int* in_sizes, int n_in,
                              void* d_out, int out_size, void* d_ws, size_t ws_size,
                              hipStream_t stream) {
    const float* x     = (const float*)d_in[0];
    const float* lap   = (const float*)d_in[1];
    const float* W_in  = (const float*)d_in[2];
    const float* b_in  = (const float*)d_in[3];
    const float* Aq    = (const float*)d_in[4];
    const float* Ak    = (const float*)d_in[5];
    const float* Av    = (const float*)d_in[6];
    const float* W_out = (const float*)d_in[7];
    const float* b_out = (const float*)d_in[8];
    attn_mfma_kernel<<<2048, 256, 0, stream>>>(x, lap, W_in, b_in, Aq, Ak, Av,
                                               W_out, b_out, (float*)d_out);
}

// Round 21
// 56.529 us; speedup vs baseline: 1.0535x; 1.0535x over previous
//
#include <hip/hip_runtime.h>

#define NB   8192
#define NA   32
#define DIN  8
#define HID  64
#define DOUT 8

typedef float     v4f __attribute__((ext_vector_type(4)));
typedef __fp16    v2fp __attribute__((ext_vector_type(2)));
typedef _Float16  v2h __attribute__((ext_vector_type(2)));
typedef _Float16  v4h __attribute__((ext_vector_type(4)));
typedef _Float16  v8h __attribute__((ext_vector_type(8)));

__device__ __forceinline__ float silu_f(float x) {
    return __fdividef(x, 1.0f + __expf(-x));
}

__device__ __forceinline__ v2h pkrtz(float a, float b) {
    v2fp r = __builtin_amdgcn_cvt_pkrtz(a, b);
    return __builtin_bit_cast(v2h, r);
}

__device__ __forceinline__ v4h cvt4(v4f a) {
    v2h lo = pkrtz(a[0], a[1]);
    v2h hi = pkrtz(a[2], a[3]);
    return __builtin_shufflevector(lo, hi, 0, 1, 2, 3);
}

__device__ __forceinline__ v8h cvt8(v4f a, v4f b) {
    v4h x = cvt4(a);
    v4h y = cvt4(b);
    return __builtin_shufflevector(x, y, 0, 1, 2, 3, 4, 5, 6, 7);
}

__device__ __forceinline__ v4h silu_cvt4(v4f a) {
    v4f s;
    s[0] = silu_f(a[0]); s[1] = silu_f(a[1]);
    s[2] = silu_f(a[2]); s[3] = silu_f(a[3]);
    return cvt4(s);
}

__device__ __forceinline__ v8h cat(v4h a, v4h b) {
    return __builtin_shufflevector(a, b, 0, 1, 2, 3, 4, 5, 6, 7);
}

// Known-good reductions (r16). permlane*_swap BANNED (r15/r17 NaN).
__device__ __forceinline__ float redmax64(float x) {
    x = fmaxf(x, __shfl_xor(x, 16, 64));
    return fmaxf(x, __shfl_xor(x, 32, 64));
}
__device__ __forceinline__ float redsum64(float x) {
    x += __shfl_xor(x, 16, 64);
    return x + __shfl_xor(x, 32, 64);
}

#define MFMA16(A, B, C) __builtin_amdgcn_mfma_f32_16x16x16f16((A), (B), (C), 0, 0, 0)
#define MFMA32(A, B, C) __builtin_amdgcn_mfma_f32_16x16x32_f16((A), (B), (C), 0, 0, 0)

// Best-known configuration (r19, 56.5us bench): one item per wave, zero
// per-item LDS (swapped h-gemm, bias folded into MFMA K-slot 8), K=32
// MFMAs, streamed attention tail, tail-only liveness for woutf/lapv/boutf.
// r20's exp2/max3 micro-opts REGRESSED (compiler already optimal there).
// Plateau analysis: total VGPR+AGPR ~160 -> 3 waves/SIMD, latency-bound at
// ~27% per-SIMD issue; crossing the 128-reg cliff needs shedding ~32 live
// regs, which the QKV fragment set structurally demands (LDS alternative
// blows the 4-block/CU budget). 14.8x over the fp32 r4 baseline.
__global__ __launch_bounds__(256, 4) void attn_mfma_kernel(
    const float* __restrict__ x,      // (NB, NA, DIN)
    const float* __restrict__ lap,    // (NB, NA)
    const float* __restrict__ W_in,   // (HID, DIN)
    const float* __restrict__ b_in,   // (HID)
    const float* __restrict__ Aq,     // (HID, HID)
    const float* __restrict__ Ak,     // (HID, HID)
    const float* __restrict__ Av,     // (HID, HID)
    const float* __restrict__ W_out,  // (DOUT, HID)
    const float* __restrict__ b_out,  // (DOUT)
    float* __restrict__ out)          // (NB, DOUT)
{
    // Paired frag-ordered f16 weights: [mat][it*2+c][lane][8]   (24 KB)
    __shared__ _Float16 wlds[3][8][64][8];

    const int t  = threadIdx.x;
    const int l  = t & 63;
    const int w  = t >> 6;          // 0..3
    const int lm = l & 15;
    const int lg = l >> 4;

    // ---- stage Aq/Ak/Av into LDS as paired f16 frags (2 fids per wave) ----
    {
        const float* mats[3] = {Aq, Ak, Av};
        #pragma unroll
        for (int m = 0; m < 3; ++m)
            #pragma unroll
            for (int f = 0; f < 2; ++f) {
                const int fid = w * 2 + f;          // it = w, c = f
                const float* base = mats[m] + (lm + 16 * w) * 64 + 32 * f + 4 * lg;
                *(v8h*)&wlds[m][fid][l][0] =
                    cvt8(*(const v4f*)base, *(const v4f*)(base + 16));
            }
    }

    // ---- h-stage register frags only (tail values loaded later) ----
    v4h zh = {};
    v4f zf = {};
    v4h winf[4];
    #pragma unroll
    for (int jt = 0; jt < 4; ++jt) {
        v4h wf = zh;
        if (lg < 2)       wf = cvt4(*(const v4f*)(W_in + (lm + 16 * jt) * 8 + 4 * lg));
        else if (lg == 2) wf[0] = (_Float16)b_in[lm + 16 * jt];
        winf[jt] = wf;
    }
    v4h onef = zh;
    if (lg == 2) onef[0] = (_Float16)1.0f;   // the k=8 "bias column" of x

    __syncthreads();   // the only block barrier

    const int b = blockIdx.x * 4 + w;   // one item per wave, 2048*4 == NB

    float lap_n[2];                      // lap by lane n=lm+16nt (h stage)
    lap_n[0] = lap[b * 32 + lm];
    lap_n[1] = lap[b * 32 + 16 + lm];

    // xf[nt]: B-frag x^T[k=d][n=lm+16nt]; k=8 slot = 1.0 (bias column)
    v4h xf[2];
    #pragma unroll
    for (int nt = 0; nt < 2; ++nt)
        xf[nt] = (lg < 2) ? cvt4(*(const v4f*)(x + b * 256 + (lm + 16 * nt) * 8 + 4 * lg))
                          : onef;

    // ---- h^T: C[jt][nt] reg r = h[n=lm+16nt][j=4lg+r+16jt] ----
    v8h hf8[2][2];
    #pragma unroll
    for (int nt = 0; nt < 2; ++nt)
        #pragma unroll
        for (int c = 0; c < 2; ++c) {
            v4f h0 = MFMA16(winf[2 * c],     xf[nt], zf);
            v4f h1 = MFMA16(winf[2 * c + 1], xf[nt], zf);
            v4f s0, s1;
            #pragma unroll
            for (int r = 0; r < 4; ++r) {
                s0[r] = silu_f(h0[r]) * lap_n[nt];
                s1[r] = silu_f(h1[r]) * lap_n[nt];
            }
            hf8[nt][c] = cat(cvt4(s0), cvt4(s1));
        }

    // ---- QT[n][i] = silu(h @ Aq^T)  (K=32) ----
    v8h qf8[4];
    {
        v4f acc[2][4] = {};
        #pragma unroll
        for (int it = 0; it < 4; ++it)
            #pragma unroll
            for (int c = 0; c < 2; ++c) {
                v8h bw = *(v8h*)&wlds[0][it * 2 + c][l][0];
                #pragma unroll
                for (int nt = 0; nt < 2; ++nt)
                    acc[nt][it] = MFMA32(hf8[nt][c], bw, acc[nt][it]);
            }
        #pragma unroll
        for (int it = 0; it < 4; ++it)
            qf8[it] = cat(silu_cvt4(acc[0][it]), silu_cvt4(acc[1][it]));
    }
    // ---- KT[n][i] = silu(h @ Ak^T) ----
    v8h kf8[4];
    {
        v4f acc[2][4] = {};
        #pragma unroll
        for (int it = 0; it < 4; ++it)
            #pragma unroll
            for (int c = 0; c < 2; ++c) {
                v8h bw = *(v8h*)&wlds[1][it * 2 + c][l][0];
                #pragma unroll
                for (int nt = 0; nt < 2; ++nt)
                    acc[nt][it] = MFMA32(hf8[nt][c], bw, acc[nt][it]);
            }
        #pragma unroll
        for (int it = 0; it < 4; ++it)
            kf8[it] = cat(silu_cvt4(acc[0][it]), silu_cvt4(acc[1][it]));
    }
    // ---- V[i][n] = silu(Av @ h^T) ----  (h dies here)
    v8h vf8[2][2];
    {
        v4f acc[4][2] = {};
        #pragma unroll
        for (int it = 0; it < 4; ++it)
            #pragma unroll
            for (int c = 0; c < 2; ++c) {
                v8h aw = *(v8h*)&wlds[2][it * 2 + c][l][0];
                #pragma unroll
                for (int nt = 0; nt < 2; ++nt)
                    acc[it][nt] = MFMA32(aw, hf8[nt][c], acc[it][nt]);
            }
        #pragma unroll
        for (int c = 0; c < 2; ++c)
            #pragma unroll
            for (int nt = 0; nt < 2; ++nt)
                vf8[c][nt] = cat(silu_cvt4(acc[2 * c][nt]), silu_cvt4(acc[2 * c + 1][nt]));
    }

    // ---- tail-only loads (liveness starts here, not at kernel entry) ----
    v4h woutf[4];
    #pragma unroll
    for (int ks = 0; ks < 4; ++ks)
        woutf[ks] = (lm < 8) ? cvt4(*(const v4f*)(W_out + lm * 64 + 16 * ks + 4 * lg)) : zh;
    const float boutf = (lm < 8) ? b_out[lm] : 0.0f;
    v4f lapv[2];
    lapv[0] = *(const v4f*)(lap + b * 32 + 4 * lg);
    lapv[1] = *(const v4f*)(lap + b * 32 + 16 + 4 * lg);

    // ---- streamed tail: per i-tile, S-col -> softmax -> PV -> Wout-acc ----
    v4f ya[2] = {};
    #pragma unroll
    for (int it = 0; it < 4; ++it) {
        v4f s[4];
        #pragma unroll
        for (int jt = 0; jt < 4; ++jt)
            s[jt] = MFMA32(kf8[jt], qf8[it], zf);

        float mx = fmaxf(fmaxf(fmaxf(s[0][0], s[0][1]), fmaxf(s[0][2], s[0][3])),
                         fmaxf(fmaxf(s[1][0], s[1][1]), fmaxf(s[1][2], s[1][3])));
        float mx2 = fmaxf(fmaxf(fmaxf(s[2][0], s[2][1]), fmaxf(s[2][2], s[2][3])),
                          fmaxf(fmaxf(s[3][0], s[3][1]), fmaxf(s[3][2], s[3][3])));
        mx = redmax64(fmaxf(mx, mx2));
        float sum = 0.0f;
        #pragma unroll
        for (int jt = 0; jt < 4; ++jt)
            #pragma unroll
            for (int r = 0; r < 4; ++r) {
                float e = __expf(s[jt][r] - mx);
                s[jt][r] = e;
                sum += e;
            }
        sum = redsum64(sum);
        const float inv = __fdividef(1.0f, sum);
        v4h pf[4];
        #pragma unroll
        for (int jt = 0; jt < 4; ++jt) pf[jt] = cvt4(s[jt] * inv);

        v4f pv[2] = {};
        #pragma unroll
        for (int c = 0; c < 2; ++c) {
            v8h pf8 = cat(pf[2 * c], pf[2 * c + 1]);
            #pragma unroll
            for (int nt = 0; nt < 2; ++nt)
                pv[nt] = MFMA32(pf8, vf8[c][nt], pv[nt]);
        }
        #pragma unroll
        for (int nt = 0; nt < 2; ++nt)
            ya[nt] = MFMA16(silu_cvt4(pv[nt]), woutf[it], ya[nt]);
    }

    // ---- y = silu(ya + b_out) * lap ; mean over n ----
    float acc = 0.0f;
    #pragma unroll
    for (int nt = 0; nt < 2; ++nt)
        #pragma unroll
        for (int r = 0; r < 4; ++r)
            acc += silu_f(ya[nt][r] + boutf) * lapv[nt][r];
    acc = redsum64(acc);
    if (l < 8) out[b * DOUT + l] = acc * (1.0f / NA);
}

extern "C" void kernel_launch(void* const* d_in, const int* in_sizes, int n_in,
                              void* d_out, int out_size, void* d_ws, size_t ws_size,
                              hipStream_t stream) {
    const float* x     = (const float*)d_in[0];
    const float* lap   = (const float*)d_in[1];
    const float* W_in  = (const float*)d_in[2];
    const float* b_in  = (const float*)d_in[3];
    const float* Aq    = (const float*)d_in[4];
    const float* Ak    = (const float*)d_in[5];
    const float* Av    = (const float*)d_in[6];
    const float* W_out = (const float*)d_in[7];
    const float* b_out = (const float*)d_in[8];
    attn_mfma_kernel<<<2048, 256, 0, stream>>>(x, lap, W_in, b_in, Aq, Ak, Av,
                                               W_out, b_out, (float*)d_out);
}

// Round 24
// 56.413 us; speedup vs baseline: 1.0557x; 1.0021x over previous
//
#include <hip/hip_runtime.h>

#define NB   8192
#define NA   32
#define DIN  8
#define HID  64
#define DOUT 8

typedef float     v4f __attribute__((ext_vector_type(4)));
typedef __fp16    v2fp __attribute__((ext_vector_type(2)));
typedef _Float16  v2h __attribute__((ext_vector_type(2)));
typedef _Float16  v4h __attribute__((ext_vector_type(4)));
typedef _Float16  v8h __attribute__((ext_vector_type(8)));

__device__ __forceinline__ float silu_f(float x) {
    return __fdividef(x, 1.0f + __expf(-x));
}

__device__ __forceinline__ v2h pkrtz(float a, float b) {
    v2fp r = __builtin_amdgcn_cvt_pkrtz(a, b);
    return __builtin_bit_cast(v2h, r);
}

__device__ __forceinline__ v4h cvt4(v4f a) {
    v2h lo = pkrtz(a[0], a[1]);
    v2h hi = pkrtz(a[2], a[3]);
    return __builtin_shufflevector(lo, hi, 0, 1, 2, 3);
}

__device__ __forceinline__ v8h cvt8(v4f a, v4f b) {
    v4h x = cvt4(a);
    v4h y = cvt4(b);
    return __builtin_shufflevector(x, y, 0, 1, 2, 3, 4, 5, 6, 7);
}

__device__ __forceinline__ v4h silu_cvt4(v4f a) {
    v4f s;
    s[0] = silu_f(a[0]); s[1] = silu_f(a[1]);
    s[2] = silu_f(a[2]); s[3] = silu_f(a[3]);
    return cvt4(s);
}

__device__ __forceinline__ v8h cat(v4h a, v4h b) {
    return __builtin_shufflevector(a, b, 0, 1, 2, 3, 4, 5, 6, 7);
}

// Known-good reductions. permlane*_swap PERMANENTLY BANNED: NaN'd three
// ways (r15 raw asm, r17 builtin, r22 builtin+forced-distinct-operand) --
// instruction semantics don't match the assumed {x[l], x[l^k]} pair model.
__device__ __forceinline__ float redmax64(float x) {
    x = fmaxf(x, __shfl_xor(x, 16, 64));
    return fmaxf(x, __shfl_xor(x, 32, 64));
}
__device__ __forceinline__ float redsum64(float x) {
    x += __shfl_xor(x, 16, 64);
    return x + __shfl_xor(x, 32, 64);
}

#define MFMA16(A, B, C) __builtin_amdgcn_mfma_f32_16x16x16f16((A), (B), (C), 0, 0, 0)
#define MFMA32(A, B, C) __builtin_amdgcn_mfma_f32_16x16x32_f16((A), (B), (C), 0, 0, 0)

// Best-known configuration (r19/r21, 56.5us bench, reproduced twice):
// one item per wave, zero per-item LDS (swapped h-gemm W_in@x^T whose
// C-frag directly chains as downstream operands; bias folded into MFMA
// K-slot 8), K=32 MFMAs, streamed attention tail, tail-only liveness for
// woutf/lapv/boutf. Plateau: unified VGPR+AGPR ~160 -> 3 waves/SIMD,
// latency-bound at ~27% per-SIMD issue; 12 structural variants (r5-r22)
// converge at 62-66us profiled. 14.8x over the fp32 r4 baseline (837us).
__global__ __launch_bounds__(256, 4) void attn_mfma_kernel(
    const float* __restrict__ x,      // (NB, NA, DIN)
    const float* __restrict__ lap,    // (NB, NA)
    const float* __restrict__ W_in,   // (HID, DIN)
    const float* __restrict__ b_in,   // (HID)
    const float* __restrict__ Aq,     // (HID, HID)
    const float* __restrict__ Ak,     // (HID, HID)
    const float* __restrict__ Av,     // (HID, HID)
    const float* __restrict__ W_out,  // (DOUT, HID)
    const float* __restrict__ b_out,  // (DOUT)
    float* __restrict__ out)          // (NB, DOUT)
{
    // Paired frag-ordered f16 weights: [mat][it*2+c][lane][8]   (24 KB)
    __shared__ _Float16 wlds[3][8][64][8];

    const int t  = threadIdx.x;
    const int l  = t & 63;
    const int w  = t >> 6;          // 0..3
    const int lm = l & 15;
    const int lg = l >> 4;

    // ---- stage Aq/Ak/Av into LDS as paired f16 frags (2 fids per wave) ----
    {
        const float* mats[3] = {Aq, Ak, Av};
        #pragma unroll
        for (int m = 0; m < 3; ++m)
            #pragma unroll
            for (int f = 0; f < 2; ++f) {
                const int fid = w * 2 + f;          // it = w, c = f
                const float* base = mats[m] + (lm + 16 * w) * 64 + 32 * f + 4 * lg;
                *(v8h*)&wlds[m][fid][l][0] =
                    cvt8(*(const v4f*)base, *(const v4f*)(base + 16));
            }
    }

    // ---- h-stage register frags only (tail values loaded later) ----
    v4h zh = {};
    v4f zf = {};
    v4h winf[4];
    #pragma unroll
    for (int jt = 0; jt < 4; ++jt) {
        v4h wf = zh;
        if (lg < 2)       wf = cvt4(*(const v4f*)(W_in + (lm + 16 * jt) * 8 + 4 * lg));
        else if (lg == 2) wf[0] = (_Float16)b_in[lm + 16 * jt];
        winf[jt] = wf;
    }
    v4h onef = zh;
    if (lg == 2) onef[0] = (_Float16)1.0f;   // the k=8 "bias column" of x

    __syncthreads();   // the only block barrier

    const int b = blockIdx.x * 4 + w;   // one item per wave, 2048*4 == NB

    float lap_n[2];                      // lap by lane n=lm+16nt (h stage)
    lap_n[0] = lap[b * 32 + lm];
    lap_n[1] = lap[b * 32 + 16 + lm];

    // xf[nt]: B-frag x^T[k=d][n=lm+16nt]; k=8 slot = 1.0 (bias column)
    v4h xf[2];
    #pragma unroll
    for (int nt = 0; nt < 2; ++nt)
        xf[nt] = (lg < 2) ? cvt4(*(const v4f*)(x + b * 256 + (lm + 16 * nt) * 8 + 4 * lg))
                          : onef;

    // ---- h^T: C[jt][nt] reg r = h[n=lm+16nt][j=4lg+r+16jt] ----
    v8h hf8[2][2];
    #pragma unroll
    for (int nt = 0; nt < 2; ++nt)
        #pragma unroll
        for (int c = 0; c < 2; ++c) {
            v4f h0 = MFMA16(winf[2 * c],     xf[nt], zf);
            v4f h1 = MFMA16(winf[2 * c + 1], xf[nt], zf);
            v4f s0, s1;
            #pragma unroll
            for (int r = 0; r < 4; ++r) {
                s0[r] = silu_f(h0[r]) * lap_n[nt];
                s1[r] = silu_f(h1[r]) * lap_n[nt];
            }
            hf8[nt][c] = cat(cvt4(s0), cvt4(s1));
        }

    // ---- QT[n][i] = silu(h @ Aq^T)  (K=32) ----
    v8h qf8[4];
    {
        v4f acc[2][4] = {};
        #pragma unroll
        for (int it = 0; it < 4; ++it)
            #pragma unroll
            for (int c = 0; c < 2; ++c) {
                v8h bw = *(v8h*)&wlds[0][it * 2 + c][l][0];
                #pragma unroll
                for (int nt = 0; nt < 2; ++nt)
                    acc[nt][it] = MFMA32(hf8[nt][c], bw, acc[nt][it]);
            }
        #pragma unroll
        for (int it = 0; it < 4; ++it)
            qf8[it] = cat(silu_cvt4(acc[0][it]), silu_cvt4(acc[1][it]));
    }
    // ---- KT[n][i] = silu(h @ Ak^T) ----
    v8h kf8[4];
    {
        v4f acc[2][4] = {};
        #pragma unroll
        for (int it = 0; it < 4; ++it)
            #pragma unroll
            for (int c = 0; c < 2; ++c) {
                v8h bw = *(v8h*)&wlds[1][it * 2 + c][l][0];
                #pragma unroll
                for (int nt = 0; nt < 2; ++nt)
                    acc[nt][it] = MFMA32(hf8[nt][c], bw, acc[nt][it]);
            }
        #pragma unroll
        for (int it = 0; it < 4; ++it)
            kf8[it] = cat(silu_cvt4(acc[0][it]), silu_cvt4(acc[1][it]));
    }
    // ---- V[i][n] = silu(Av @ h^T) ----  (h dies here)
    v8h vf8[2][2];
    {
        v4f acc[4][2] = {};
        #pragma unroll
        for (int it = 0; it < 4; ++it)
            #pragma unroll
            for (int c = 0; c < 2; ++c) {
                v8h aw = *(v8h*)&wlds[2][it * 2 + c][l][0];
                #pragma unroll
                for (int nt = 0; nt < 2; ++nt)
                    acc[it][nt] = MFMA32(aw, hf8[nt][c], acc[it][nt]);
            }
        #pragma unroll
        for (int c = 0; c < 2; ++c)
            #pragma unroll
            for (int nt = 0; nt < 2; ++nt)
                vf8[c][nt] = cat(silu_cvt4(acc[2 * c][nt]), silu_cvt4(acc[2 * c + 1][nt]));
    }

    // ---- tail-only loads (liveness starts here, not at kernel entry) ----
    v4h woutf[4];
    #pragma unroll
    for (int ks = 0; ks < 4; ++ks)
        woutf[ks] = (lm < 8) ? cvt4(*(const v4f*)(W_out + lm * 64 + 16 * ks + 4 * lg)) : zh;
    const float boutf = (lm < 8) ? b_out[lm] : 0.0f;
    v4f lapv[2];
    lapv[0] = *(const v4f*)(lap + b * 32 + 4 * lg);
    lapv[1] = *(const v4f*)(lap + b * 32 + 16 + 4 * lg);

    // ---- streamed tail: per i-tile, S-col -> softmax -> PV -> Wout-acc ----
    v4f ya[2] = {};
    #pragma unroll
    for (int it = 0; it < 4; ++it) {
        v4f s[4];
        #pragma unroll
        for (int jt = 0; jt < 4; ++jt)
            s[jt] = MFMA32(kf8[jt], qf8[it], zf);

        float mx = fmaxf(fmaxf(fmaxf(s[0][0], s[0][1]), fmaxf(s[0][2], s[0][3])),
                         fmaxf(fmaxf(s[1][0], s[1][1]), fmaxf(s[1][2], s[1][3])));
        float mx2 = fmaxf(fmaxf(fmaxf(s[2][0], s[2][1]), fmaxf(s[2][2], s[2][3])),
                          fmaxf(fmaxf(s[3][0], s[3][1]), fmaxf(s[3][2], s[3][3])));
        mx = redmax64(fmaxf(mx, mx2));
        float sum = 0.0f;
        #pragma unroll
        for (int jt = 0; jt < 4; ++jt)
            #pragma unroll
            for (int r = 0; r < 4; ++r) {
                float e = __expf(s[jt][r] - mx);
                s[jt][r] = e;
                sum += e;
            }
        sum = redsum64(sum);
        const float inv = __fdividef(1.0f, sum);
        v4h pf[4];
        #pragma unroll
        for (int jt = 0; jt < 4; ++jt) pf[jt] = cvt4(s[jt] * inv);

        v4f pv[2] = {};
        #pragma unroll
        for (int c = 0; c < 2; ++c) {
            v8h pf8 = cat(pf[2 * c], pf[2 * c + 1]);
            #pragma unroll
            for (int nt = 0; nt < 2; ++nt)
                pv[nt] = MFMA32(pf8, vf8[c][nt], pv[nt]);
        }
        #pragma unroll
        for (int nt = 0; nt < 2; ++nt)
            ya[nt] = MFMA16(silu_cvt4(pv[nt]), woutf[it], ya[nt]);
    }

    // ---- y = silu(ya + b_out) * lap ; mean over n ----
    float acc = 0.0f;
    #pragma unroll
    for (int nt = 0; nt < 2; ++nt)
        #pragma unroll
        for (int r = 0; r < 4; ++r)
            acc += silu_f(ya[nt][r] + boutf) * lapv[nt][r];
    acc = redsum64(acc);
    if (l < 8) out[b * DOUT + l] = acc * (1.0f / NA);
}

extern "C" void kernel_launch(void* const* d_in, const int* in_sizes, int n_in,
                              void* d_out, int out_size, void* d_ws, size_t ws_size,
                              hipStream_t stream) {
    const float* x     = (const float*)d_in[0];
    const float* lap   = (const float*)d_in[1];
    const float* W_in  = (const float*)d_in[2];
    const float* b_in  = (const float*)d_in[3];
    const float* Aq    = (const float*)d_in[4];
    const float* Ak    = (const float*)d_in[5];
    const float* Av    = (const float*)d_in[6];
    const float* W_out = (const float*)d_in[7];
    const float* b_out = (const float*)d_in[8];
    attn_mfma_kernel<<<2048, 256, 0, stream>>>(x, lap, W_in, b_in, Aq, Ak, Av,
                                               W_out, b_out, (float*)d_out);
}